// Round 1
// 2769.683 us; speedup vs baseline: 1.3568x; 1.3568x over previous
//
#include <hip/hip_runtime.h>
#include <hip/hip_bf16.h>
#include <math.h>

#define CC 768
#define TT 512
#define BB 2
#define HH 12
#define KV 64
#define LL 6
#define VV 50304
#define DFF 2688
#define MM (BB*TT)   // 1024

typedef unsigned short ushort_t;
typedef __attribute__((ext_vector_type(8))) short short8;
typedef __attribute__((ext_vector_type(4))) float floatx4;

__device__ __forceinline__ unsigned short f2b(float f) {
    union { float f; unsigned u; } v; v.f = f;
    unsigned r = (v.u + 0x7fffu + ((v.u >> 16) & 1u)) >> 16;
    return (unsigned short)r;
}

__device__ __forceinline__ void async16(const void* g, const void* l) {
    __builtin_amdgcn_global_load_lds((const __attribute__((address_space(1))) unsigned int*)g,
                                     (__attribute__((address_space(3))) unsigned int*)l, 16, 0, 0);
}

// ---------------- block reduce ----------------
__device__ __forceinline__ float block_reduce_sum256(float v, float* red) {
    int tid = threadIdx.x;
    red[tid] = v; __syncthreads();
    #pragma unroll
    for (int s = 128; s > 0; s >>= 1) {
        if (tid < s) red[tid] += red[tid + s];
        __syncthreads();
    }
    float r = red[0];
    __syncthreads();
    return r;
}

// ---------------- LayerNorm over C=768 (optionally gathering embed rows, optional bf16 out) ----
__global__ __launch_bounds__(256) void ln_kernel(
        const float* __restrict__ in, const int* __restrict__ tokens,
        const float* __restrict__ s, const float* __restrict__ b,
        float* __restrict__ out, unsigned short* __restrict__ outb) {
    __shared__ float red[256];
    int row = blockIdx.x;
    int tid = threadIdx.x;
    const float* x = in + (size_t)(tokens ? tokens[row] : row) * CC;
    float x0 = x[tid], x1 = x[tid + 256], x2 = x[tid + 512];
    float total = block_reduce_sum256(x0 + x1 + x2, red);
    float mean = total * (1.f / 768.f);
    float d0 = x0 - mean, d1 = x1 - mean, d2 = x2 - mean;
    float var = block_reduce_sum256(d0*d0 + d1*d1 + d2*d2, red) * (1.f / 768.f);
    float inv = rsqrtf(var + 1e-5f);
    float o0 = d0 * inv * s[tid]       + b[tid];
    float o1 = d1 * inv * s[tid + 256] + b[tid + 256];
    float o2 = d2 * inv * s[tid + 512] + b[tid + 512];
    float* o = out + (size_t)row * CC;
    o[tid] = o0; o[tid + 256] = o1; o[tid + 512] = o2;
    if (outb) {
        unsigned short* ob = outb + (size_t)row * CC;
        ob[tid] = f2b(o0); ob[tid + 256] = f2b(o1); ob[tid + 512] = f2b(o2);
    }
}

// ---------------- build A = [x, xs] bf16, [MM][1536] ----------------
__global__ __launch_bounds__(256) void build_a_kernel(
        const float* __restrict__ lnb, unsigned short* __restrict__ abuf) {
    int i = blockIdx.x * 256 + threadIdx.x;   // over MM*192 float4s
    int c4 = i % 192;
    int row = i / 192;
    float4 x = ((const float4*)lnb)[i];
    ushort4 o0; o0.x = f2b(x.x); o0.y = f2b(x.y); o0.z = f2b(x.z); o0.w = f2b(x.w);
    ((ushort4*)(abuf + (size_t)row * 1536))[c4] = o0;
    float4 xs;
    if ((row % TT) == 0) xs = make_float4(0.f, 0.f, 0.f, 0.f);
    else xs = ((const float4*)lnb)[i - 192];
    ushort4 o1; o1.x = f2b(xs.x); o1.y = f2b(xs.y); o1.z = f2b(xs.z); o1.w = f2b(xs.w);
    ((ushort4*)(abuf + (size_t)row * 1536 + 768))[c4] = o1;
}

// ---------------- weight convert fp32->bf16 ----------------
__global__ __launch_bounds__(256) void convertw_kernel(
        const float* __restrict__ src, unsigned short* __restrict__ dst, int n4) {
    int i = blockIdx.x * 256 + threadIdx.x;
    if (i >= n4) return;
    float4 v = ((const float4*)src)[i];
    ushort4 o; o.x = f2b(v.x); o.y = f2b(v.y); o.z = f2b(v.z); o.w = f2b(v.w);
    ((ushort4*)dst)[i] = o;
}

// ---------------- weight pack with lerp fold: dst[n][c]=W*(1-t), dst[n][K+c]=W*t ------------
__global__ __launch_bounds__(256) void packw_kernel(
        const float* __restrict__ W, const float* __restrict__ t,
        unsigned short* __restrict__ dst, int K, int n4) {
    int i = blockIdx.x * 256 + threadIdx.x;
    if (i >= n4) return;
    int K4 = K >> 2;
    int row = i / K4, c4 = i % K4;
    float4 w = ((const float4*)W)[i];
    float4 tv = ((const float4*)t)[c4];
    ushort4 a, bq;
    a.x = f2b(w.x * (1.f - tv.x)); a.y = f2b(w.y * (1.f - tv.y));
    a.z = f2b(w.z * (1.f - tv.z)); a.w = f2b(w.w * (1.f - tv.w));
    bq.x = f2b(w.x * tv.x); bq.y = f2b(w.y * tv.y);
    bq.z = f2b(w.z * tv.z); bq.w = f2b(w.w * tv.w);
    ushort4* drow = (ushort4*)(dst + (size_t)row * 2 * K);
    drow[c4] = a;
    ((ushort4*)(dst + (size_t)row * 2 * K + K))[c4] = bq;
}

// ---------------- bf16 MFMA GEMM: C = epi(A @ B^T) ----------------
// A: M x K bf16 row-major; B: N x K bf16 row-major. BM=128, BK=32, BN in {128,64}.
// 256 threads = 4 waves in 2x2; wave tile (64)x(BN/2); 16x16x32 MFMA frags.
// mode 0: Cf=acc (ld N); 1: Cf=acc+res; 2: Cf=acc*mul+res; 3: split at NS:
//   col<NS: Cb[row*NS+col]=bf16(relu(acc)^2); col>=NS: Cf[row*(N-NS)+col-NS]=sigmoid(acc)
template<int BN>
__global__ __launch_bounds__(256) void mfma_gemm_kernel(
        const unsigned short* __restrict__ A, const unsigned short* __restrict__ B,
        float* __restrict__ Cf, unsigned short* __restrict__ Cb,
        int M, int N, int K, int mode, int NS,
        const float* __restrict__ mul, const float* __restrict__ res) {
    constexpr int BM = 128, BK = 32;
    constexpr int FN = BN / 32;
    __shared__ __align__(16) unsigned short As[BM * BK];
    __shared__ __align__(16) unsigned short Bs[BN * BK];
    const int tid = threadIdx.x;
    const int lane = tid & 63;
    const int w = tid >> 6;
    const int wm = w >> 1, wn = w & 1;
    const int m0 = blockIdx.y * BM, n0 = blockIdx.x * BN;
    const int quad = lane >> 4;
    const int l16 = lane & 15;

    floatx4 acc[4][FN];
    #pragma unroll
    for (int i = 0; i < 4; i++)
        #pragma unroll
        for (int j = 0; j < FN; j++) acc[i][j] = (floatx4){0.f, 0.f, 0.f, 0.f};

    int a_off[4], b_off[FN];
    #pragma unroll
    for (int mi = 0; mi < 4; mi++)
        a_off[mi] = (wm * 64 + mi * 16 + l16) * BK + quad * 8;
    #pragma unroll
    for (int ni = 0; ni < FN; ni++)
        b_off[ni] = (wn * (BN / 2) + ni * 16 + l16) * BK + quad * 8;

    for (int k0 = 0; k0 < K; k0 += BK) {
        const unsigned short* Ag = A + (size_t)m0 * K + k0;
        const unsigned short* Bg = B + (size_t)n0 * K + k0;
        #pragma unroll
        for (int i = 0; i < BM / 64; i++) {
            int c = i * 256 + tid;
            async16(Ag + (size_t)(c >> 2) * K + (c & 3) * 8, As + (i * 256 + w * 64) * 8);
        }
        #pragma unroll
        for (int i = 0; i < BN / 64; i++) {
            int c = i * 256 + tid;
            async16(Bg + (size_t)(c >> 2) * K + (c & 3) * 8, Bs + (i * 256 + w * 64) * 8);
        }
        __syncthreads();
        short8 af[4], bfr[FN];
        #pragma unroll
        for (int mi = 0; mi < 4; mi++) af[mi] = *(const short8*)(As + a_off[mi]);
        #pragma unroll
        for (int ni = 0; ni < FN; ni++) bfr[ni] = *(const short8*)(Bs + b_off[ni]);
        #pragma unroll
        for (int mi = 0; mi < 4; mi++)
            #pragma unroll
            for (int ni = 0; ni < FN; ni++)
                acc[mi][ni] = __builtin_amdgcn_mfma_f32_16x16x32_bf16(af[mi], bfr[ni], acc[mi][ni], 0, 0, 0);
        __syncthreads();
    }

    #pragma unroll
    for (int mi = 0; mi < 4; mi++) {
        #pragma unroll
        for (int ni = 0; ni < FN; ni++) {
            int col = n0 + wn * (BN / 2) + ni * 16 + l16;
            int row0 = m0 + wm * 64 + mi * 16 + quad * 4;
            #pragma unroll
            for (int r = 0; r < 4; r++) {
                float vval = acc[mi][ni][r];
                int row = row0 + r;
                if (mode == 0) {
                    Cf[(size_t)row * N + col] = vval;
                } else if (mode == 1) {
                    size_t off = (size_t)row * N + col;
                    Cf[off] = vval + res[off];
                } else if (mode == 2) {
                    size_t off = (size_t)row * N + col;
                    Cf[off] = vval * mul[off] + res[off];
                } else {
                    if (col < NS) {
                        float tpos = vval > 0.f ? vval : 0.f;
                        Cb[(size_t)row * NS + col] = f2b(tpos * tpos);
                    } else {
                        float sg = 1.f / (1.f + __expf(-vval));
                        Cf[(size_t)row * (N - NS) + (col - NS)] = sg;
                    }
                }
            }
        }
    }
}

// ---------------- WKV sequential scan (barrier-free, wave-per-(b,h,v4)) ----------------
// rkvg layout: [row][3072]: r at +0, k at +768, v at +1536 (g at +2304 unused here)
// grid = BB*HH*16 blocks of 64 threads (1 wave). Each wave owns 4 v-columns.
// lane = vi*16 + kg: vi = lane>>4 (v within group), kg = lane&15 (k-group of 4).
// Each thread holds kv-state for 4 k's of its v. k-reduce = shfl_xor 1/2/4/8 (in-row DPP).
__global__ __launch_bounds__(64) void wkv_kernel(
        const float* __restrict__ rkvg, const float* __restrict__ bonus,
        const float* __restrict__ decay, float* __restrict__ out) {
    const int blk = blockIdx.x;
    const int wv = blk & 15;           // which group of 4 v-columns
    const int bh = blk >> 4;
    const int b = bh / HH, h = bh % HH;
    const int lane = threadIdx.x;      // 0..63
    const int kg = lane & 15;          // k-group: owns k in [kg*4, kg*4+4)
    const int vi = lane >> 4;          // 0..3
    const int vcol = wv * 4 + vi;

    float u_reg[4], w_reg[4], kv[4];
    #pragma unroll
    for (int j = 0; j < 4; j++) {
        int kidx = kg * 4 + j;
        u_reg[j] = bonus[h * KV + kidx];
        w_reg[j] = expf(-expf(decay[h * KV + kidx]));
        kv[j] = 0.f;
    }

    const float* base = rkvg + (size_t)(b * TT) * 3072 + h * KV;
    const float* rp = base + kg * 4;
    const float* kp = base + 768 + kg * 4;
    const float* vp = base + 1536 + vcol;
    float* op = out + (size_t)(b * TT) * CC + h * KV + vcol;

    // 2-deep prefetch: slots for t and t+1
    float4 r0 = *(const float4*)rp;
    float4 k0 = *(const float4*)kp;
    float  v0 = *vp;
    float4 r1 = *(const float4*)(rp + 3072);
    float4 k1 = *(const float4*)(kp + 3072);
    float  v1 = *(vp + 3072);

    #pragma unroll 4
    for (int t = 0; t < TT; t++) {
        float4 rc = r0, kc = k0; float vc = v0;
        r0 = r1; k0 = k1; v0 = v1;
        if (t + 2 < TT) {
            size_t off = (size_t)(t + 2) * 3072;
            r1 = *(const float4*)(rp + off);
            k1 = *(const float4*)(kp + off);
            v1 = *(vp + off);
        }
        float psum;
        {
            float a0 = kc.x * vc;
            psum  = rc.x * fmaf(u_reg[0], a0, kv[0]);
            kv[0] = fmaf(kv[0], w_reg[0], a0);
            float a1 = kc.y * vc;
            psum += rc.y * fmaf(u_reg[1], a1, kv[1]);
            kv[1] = fmaf(kv[1], w_reg[1], a1);
            float a2 = kc.z * vc;
            psum += rc.z * fmaf(u_reg[2], a2, kv[2]);
            kv[2] = fmaf(kv[2], w_reg[2], a2);
            float a3 = kc.w * vc;
            psum += rc.w * fmaf(u_reg[3], a3, kv[3]);
            kv[3] = fmaf(kv[3], w_reg[3], a3);
        }
        // reduce over the 16 kg lanes of this row (k-dimension)
        psum += __shfl_xor(psum, 1);
        psum += __shfl_xor(psum, 2);
        psum += __shfl_xor(psum, 4);
        psum += __shfl_xor(psum, 8);
        if (kg == 0) op[(size_t)t * CC] = psum;
    }
}

// ---------------- GroupNorm(eps=0.00064) * silu(g) -> bf16 ----------------
__global__ __launch_bounds__(64) void gn_silu_kernel(
        const float* __restrict__ wkvo, const float* __restrict__ rkvg,
        const float* __restrict__ gs, const float* __restrict__ gb,
        unsigned short* __restrict__ outb) {
    int gi = blockIdx.x;           // row*HH + h
    int vi = threadIdx.x;          // 0..63
    int h = gi % HH;
    int row = gi / HH;
    float val = wkvo[(size_t)gi * 64 + vi];
    float s1 = val;
    #pragma unroll
    for (int off = 32; off >= 1; off >>= 1) s1 += __shfl_xor(s1, off);
    float m = s1 * (1.f / 64.f);
    float d = val - m;
    float s2 = d * d;
    #pragma unroll
    for (int off = 32; off >= 1; off >>= 1) s2 += __shfl_xor(s2, off);
    float inv = rsqrtf(s2 * (1.f / 64.f) + 0.00064f);
    int c = h * 64 + vi;
    float gg = rkvg[(size_t)row * 3072 + 2304 + c];
    float sig = 1.f / (1.f + __expf(-gg));
    outb[(size_t)row * CC + c] = f2b((d * inv * gs[c] + gb[c]) * (gg * sig));
}

// ---------------- host ----------------
extern "C" void kernel_launch(void* const* d_in, const int* in_sizes, int n_in,
                              void* d_out, int out_size, void* d_ws, size_t ws_size,
                              hipStream_t stream) {
    const int*   tokens    = (const int*)  d_in[0];
    const float* embed     = (const float*)d_in[1];
    const float* emb_ln_s  = (const float*)d_in[2];
    const float* emb_ln_b  = (const float*)d_in[3];
    const float* tm_ln_s   = (const float*)d_in[4];
    const float* tm_ln_b   = (const float*)d_in[5];
    const float* ts_r      = (const float*)d_in[6];
    const float* ts_k      = (const float*)d_in[7];
    const float* ts_v      = (const float*)d_in[8];
    const float* ts_g      = (const float*)d_in[9];
    const float* W_r       = (const float*)d_in[10];
    const float* W_k       = (const float*)d_in[11];
    const float* W_v       = (const float*)d_in[12];
    const float* W_g       = (const float*)d_in[13];
    const float* W_o       = (const float*)d_in[14];
    const float* bonus     = (const float*)d_in[15];
    const float* decay     = (const float*)d_in[16];
    const float* gn_s      = (const float*)d_in[17];
    const float* gn_b      = (const float*)d_in[18];
    const float* cm_ln_s   = (const float*)d_in[19];
    const float* cm_ln_b   = (const float*)d_in[20];
    const float* cm_ts_in  = (const float*)d_in[21];
    const float* cm_ts_g   = (const float*)d_in[22];
    const float* W_in      = (const float*)d_in[23];
    const float* W_out     = (const float*)d_in[24];
    const float* W_gate    = (const float*)d_in[25];
    const float* head_ln_s = (const float*)d_in[26];
    const float* head_ln_b = (const float*)d_in[27];
    const float* W_unembed = (const float*)d_in[28];

    char* wsb = (char*)d_ws;
    // fp32 buffers
    float* hbuf = (float*)wsb;                 wsb += (size_t)MM * CC * 4;
    float* lnb  = (float*)wsb;                 wsb += (size_t)MM * CC * 4;
    float* rkvg = (float*)wsb;                 wsb += (size_t)MM * 3072 * 4;
    float* wkvo = (float*)wsb;                 wsb += (size_t)MM * CC * 4;
    float* gate = (float*)wsb;                 wsb += (size_t)MM * CC * 4;
    // bf16 buffers
    unsigned short* abuf   = (unsigned short*)wsb; wsb += (size_t)MM * 1536 * 2;
    unsigned short* tmo_b  = (unsigned short*)wsb; wsb += (size_t)MM * CC * 2;
    unsigned short* hid_b  = (unsigned short*)wsb; wsb += (size_t)MM * DFF * 2;
    unsigned short* lnh_b  = (unsigned short*)wsb; wsb += (size_t)MM * CC * 2;
    unsigned short* Wrkvg_b= (unsigned short*)wsb; wsb += (size_t)3072 * 1536 * 2;
    unsigned short* Wig_b  = (unsigned short*)wsb; wsb += (size_t)3456 * 1536 * 2;
    unsigned short* Wo_b   = (unsigned short*)wsb; wsb += (size_t)CC * CC * 2;
    unsigned short* Wout_b = (unsigned short*)wsb; wsb += (size_t)CC * DFF * 2;
    unsigned short* Wu_b   = (unsigned short*)wsb; wsb += (size_t)VV * CC * 2;

    dim3 b256(256);
    const int n4_cc = CC * CC / 4;        // 147456
    const int n4_ff = DFF * CC / 4;       // 516096
    const int n4_un = VV * CC / 4;        // 9658368

    // embedding + LN
    ln_kernel<<<dim3(MM), b256, 0, stream>>>(embed, tokens, emb_ln_s, emb_ln_b, hbuf, nullptr);

    for (int l = 0; l < LL; l++) {
        const float* Wr = W_r + (size_t)l * CC * CC;
        const float* Wk = W_k + (size_t)l * CC * CC;
        const float* Wv = W_v + (size_t)l * CC * CC;
        const float* Wg = W_g + (size_t)l * CC * CC;
        const float* Wo = W_o + (size_t)l * CC * CC;
        const float* Wi = W_in  + (size_t)l * DFF * CC;
        const float* Wu = W_out + (size_t)l * CC * DFF;
        const float* Wgt= W_gate+ (size_t)l * CC * CC;

        // ---- time mixer ----
        // pack W_{r,k,v,g} (lerp-folded) into Wrkvg_b [3072][1536]
        packw_kernel<<<dim3((n4_cc + 255) / 256), b256, 0, stream>>>(Wr, ts_r + l*CC, Wrkvg_b,                        CC, n4_cc);
        packw_kernel<<<dim3((n4_cc + 255) / 256), b256, 0, stream>>>(Wk, ts_k + l*CC, Wrkvg_b + (size_t) 768 * 1536, CC, n4_cc);
        packw_kernel<<<dim3((n4_cc + 255) / 256), b256, 0, stream>>>(Wv, ts_v + l*CC, Wrkvg_b + (size_t)1536 * 1536, CC, n4_cc);
        packw_kernel<<<dim3((n4_cc + 255) / 256), b256, 0, stream>>>(Wg, ts_g + l*CC, Wrkvg_b + (size_t)2304 * 1536, CC, n4_cc);
        convertw_kernel<<<dim3((n4_cc + 255) / 256), b256, 0, stream>>>(Wo, Wo_b, n4_cc);

        ln_kernel<<<dim3(MM), b256, 0, stream>>>(hbuf, nullptr, tm_ln_s + l*CC, tm_ln_b + l*CC, lnb, nullptr);
        build_a_kernel<<<dim3(MM * 192 / 256), b256, 0, stream>>>(lnb, abuf);
        // rkvg = [x,xs] @ Wrkvg^T : M=1024, N=3072, K=1536
        mfma_gemm_kernel<128><<<dim3(3072/128, MM/128), b256, 0, stream>>>(
            abuf, Wrkvg_b, rkvg, nullptr, MM, 3072, 1536, 0, 0, nullptr, nullptr);
        wkv_kernel<<<dim3(BB*HH*16), dim3(64), 0, stream>>>(rkvg, bonus + l*HH*KV, decay + l*HH*KV, wkvo);
        gn_silu_kernel<<<dim3(MM*HH), dim3(64), 0, stream>>>(wkvo, rkvg, gn_s + l*CC, gn_b + l*CC, tmo_b);
        // h += tmo @ Wo^T : N=768, K=768 (BN=64 for occupancy)
        mfma_gemm_kernel<64><<<dim3(CC/64, MM/128), b256, 0, stream>>>(
            tmo_b, Wo_b, hbuf, nullptr, MM, CC, CC, 1, 0, nullptr, hbuf);

        // ---- channel mixer ----
        packw_kernel<<<dim3((n4_ff + 255) / 256), b256, 0, stream>>>(Wi,  cm_ts_in + l*CC, Wig_b,                       CC, n4_ff);
        packw_kernel<<<dim3((n4_cc + 255) / 256), b256, 0, stream>>>(Wgt, cm_ts_g  + l*CC, Wig_b + (size_t)DFF * 1536, CC, n4_cc);
        convertw_kernel<<<dim3((n4_ff + 255) / 256), b256, 0, stream>>>(Wu, Wout_b, n4_ff);

        ln_kernel<<<dim3(MM), b256, 0, stream>>>(hbuf, nullptr, cm_ln_s + l*CC, cm_ln_b + l*CC, lnb, nullptr);
        build_a_kernel<<<dim3(MM * 192 / 256), b256, 0, stream>>>(lnb, abuf);
        // [hid | gate] = [x,xs] @ Wig^T : N=3456, K=1536, split epilogue at NS=2688
        mfma_gemm_kernel<128><<<dim3(3456/128, MM/128), b256, 0, stream>>>(
            abuf, Wig_b, gate, hid_b, MM, 3456, 1536, 3, DFF, nullptr, nullptr);
        // h += (hid @ Wout^T) * gate : N=768, K=2688
        mfma_gemm_kernel<64><<<dim3(CC/64, MM/128), b256, 0, stream>>>(
            hid_b, Wout_b, hbuf, nullptr, MM, CC, DFF, 2, 0, gate, hbuf);
    }

    // head LN + unembed
    ln_kernel<<<dim3(MM), b256, 0, stream>>>(hbuf, nullptr, head_ln_s, head_ln_b, lnb, lnh_b);
    convertw_kernel<<<dim3((n4_un + 255) / 256), b256, 0, stream>>>(W_unembed, Wu_b, n4_un);
    mfma_gemm_kernel<128><<<dim3(VV/128, MM/128), b256, 0, stream>>>(
        lnh_b, Wu_b, (float*)d_out, nullptr, MM, VV, CC, 0, 0, nullptr, nullptr);
}

// Round 2
// 2678.203 us; speedup vs baseline: 1.4031x; 1.0342x over previous
//
#include <hip/hip_runtime.h>
#include <hip/hip_bf16.h>
#include <math.h>

#define CC 768
#define TT 512
#define BB 2
#define HH 12
#define KV 64
#define LL 6
#define VV 50304
#define DFF 2688
#define MM (BB*TT)   // 1024

typedef unsigned short ushort_t;
typedef __attribute__((ext_vector_type(8))) short short8;
typedef __attribute__((ext_vector_type(4))) float floatx4;

__device__ __forceinline__ unsigned short f2b(float f) {
    union { float f; unsigned u; } v; v.f = f;
    unsigned r = (v.u + 0x7fffu + ((v.u >> 16) & 1u)) >> 16;
    return (unsigned short)r;
}

__device__ __forceinline__ void async16(const void* g, const void* l) {
    __builtin_amdgcn_global_load_lds((const __attribute__((address_space(1))) unsigned int*)g,
                                     (__attribute__((address_space(3))) unsigned int*)l, 16, 0, 0);
}

// ---------------- block reduce ----------------
__device__ __forceinline__ float block_reduce_sum256(float v, float* red) {
    int tid = threadIdx.x;
    red[tid] = v; __syncthreads();
    #pragma unroll
    for (int s = 128; s > 0; s >>= 1) {
        if (tid < s) red[tid] += red[tid + s];
        __syncthreads();
    }
    float r = red[0];
    __syncthreads();
    return r;
}

// ---------------- LayerNorm over C=768 (optionally gathering embed rows, optional bf16 out) ----
__global__ __launch_bounds__(256) void ln_kernel(
        const float* __restrict__ in, const int* __restrict__ tokens,
        const float* __restrict__ s, const float* __restrict__ b,
        float* __restrict__ out, unsigned short* __restrict__ outb) {
    __shared__ float red[256];
    int row = blockIdx.x;
    int tid = threadIdx.x;
    const float* x = in + (size_t)(tokens ? tokens[row] : row) * CC;
    float x0 = x[tid], x1 = x[tid + 256], x2 = x[tid + 512];
    float total = block_reduce_sum256(x0 + x1 + x2, red);
    float mean = total * (1.f / 768.f);
    float d0 = x0 - mean, d1 = x1 - mean, d2 = x2 - mean;
    float var = block_reduce_sum256(d0*d0 + d1*d1 + d2*d2, red) * (1.f / 768.f);
    float inv = rsqrtf(var + 1e-5f);
    float o0 = d0 * inv * s[tid]       + b[tid];
    float o1 = d1 * inv * s[tid + 256] + b[tid + 256];
    float o2 = d2 * inv * s[tid + 512] + b[tid + 512];
    float* o = out + (size_t)row * CC;
    o[tid] = o0; o[tid + 256] = o1; o[tid + 512] = o2;
    if (outb) {
        unsigned short* ob = outb + (size_t)row * CC;
        ob[tid] = f2b(o0); ob[tid + 256] = f2b(o1); ob[tid + 512] = f2b(o2);
    }
}

// ---------------- fused LN -> A=[x,xs] bf16 [MM][1536] ----------------
// Row r writes bf16(x_r) into abuf[r][0:768] and into abuf[r+1][768:1536]
// (the shift slot of the NEXT row); sequence-start rows zero their own shift slot.
__global__ __launch_bounds__(256) void ln_a_kernel(
        const float* __restrict__ in,
        const float* __restrict__ s, const float* __restrict__ b,
        unsigned short* __restrict__ abuf) {
    __shared__ float red[256];
    int row = blockIdx.x;
    int tid = threadIdx.x;
    const float* x = in + (size_t)row * CC;
    float x0 = x[tid], x1 = x[tid + 256], x2 = x[tid + 512];
    float total = block_reduce_sum256(x0 + x1 + x2, red);
    float mean = total * (1.f / 768.f);
    float d0 = x0 - mean, d1 = x1 - mean, d2 = x2 - mean;
    float var = block_reduce_sum256(d0*d0 + d1*d1 + d2*d2, red) * (1.f / 768.f);
    float inv = rsqrtf(var + 1e-5f);
    unsigned short o0 = f2b(d0 * inv * s[tid]       + b[tid]);
    unsigned short o1 = f2b(d1 * inv * s[tid + 256] + b[tid + 256]);
    unsigned short o2 = f2b(d2 * inv * s[tid + 512] + b[tid + 512]);
    unsigned short* arow = abuf + (size_t)row * 1536;
    arow[tid] = o0; arow[tid + 256] = o1; arow[tid + 512] = o2;
    if ((row % TT) == 0) {
        arow[768 + tid] = 0; arow[768 + tid + 256] = 0; arow[768 + tid + 512] = 0;
    }
    int nrow = row + 1;
    if (nrow < MM && (nrow % TT) != 0) {
        unsigned short* nx = abuf + (size_t)nrow * 1536 + 768;
        nx[tid] = o0; nx[tid + 256] = o1; nx[tid + 512] = o2;
    }
}

// ---------------- weight convert fp32->bf16 (standalone, for unembed) ----------------
__global__ __launch_bounds__(256) void convertw_kernel(
        const float* __restrict__ src, unsigned short* __restrict__ dst, int n4) {
    int i = blockIdx.x * 256 + threadIdx.x;
    if (i >= n4) return;
    float4 v = ((const float4*)src)[i];
    ushort4 o; o.x = f2b(v.x); o.y = f2b(v.y); o.z = f2b(v.z); o.w = f2b(v.w);
    ((ushort4*)dst)[i] = o;
}

// ---------------- device helpers for fused prep ----------------
__device__ __forceinline__ void packw_body(
        const float* __restrict__ W, const float* __restrict__ t,
        unsigned short* __restrict__ dst, int K, int i) {
    int K4 = K >> 2;
    int row = i / K4, c4 = i % K4;
    float4 w = ((const float4*)W)[i];
    float4 tv = ((const float4*)t)[c4];
    ushort4 a, bq;
    a.x = f2b(w.x * (1.f - tv.x)); a.y = f2b(w.y * (1.f - tv.y));
    a.z = f2b(w.z * (1.f - tv.z)); a.w = f2b(w.w * (1.f - tv.w));
    bq.x = f2b(w.x * tv.x); bq.y = f2b(w.y * tv.y);
    bq.z = f2b(w.z * tv.z); bq.w = f2b(w.w * tv.w);
    ((ushort4*)(dst + (size_t)row * 2 * K))[c4] = a;
    ((ushort4*)(dst + (size_t)row * 2 * K + K))[c4] = bq;
}

__device__ __forceinline__ void convert_body(
        const float* __restrict__ src, unsigned short* __restrict__ dst, int i) {
    float4 v = ((const float4*)src)[i];
    ushort4 o; o.x = f2b(v.x); o.y = f2b(v.y); o.z = f2b(v.z); o.w = f2b(v.w);
    ((ushort4*)dst)[i] = o;
}

// TM prep: 5 segments of 576 blocks each (n4_cc = 576*256): pack Wr/Wk/Wv/Wg + convert Wo
__global__ __launch_bounds__(256) void prep_tm_kernel(
        const float* __restrict__ Wr, const float* __restrict__ Wk,
        const float* __restrict__ Wv, const float* __restrict__ Wg,
        const float* __restrict__ Wo,
        const float* __restrict__ tr, const float* __restrict__ tk,
        const float* __restrict__ tv, const float* __restrict__ tg,
        unsigned short* __restrict__ Wrkvg_b, unsigned short* __restrict__ Wo_b) {
    int blk = blockIdx.x;
    int seg = blk / 576;
    int i = (blk % 576) * 256 + threadIdx.x;
    if (seg == 4) { convert_body(Wo, Wo_b, i); return; }
    const float* W = (seg == 0) ? Wr : (seg == 1) ? Wk : (seg == 2) ? Wv : Wg;
    const float* t = (seg == 0) ? tr : (seg == 1) ? tk : (seg == 2) ? tv : tg;
    packw_body(W, t, Wrkvg_b + (size_t)seg * 768 * 1536, CC, i);
}

// CM prep: [0,2016) pack Wi; [2016,2592) pack Wgate; [2592,4608) convert Wout
__global__ __launch_bounds__(256) void prep_cm_kernel(
        const float* __restrict__ Wi, const float* __restrict__ Wgt,
        const float* __restrict__ Wu,
        const float* __restrict__ tin, const float* __restrict__ tg,
        unsigned short* __restrict__ Wig_b, unsigned short* __restrict__ Wout_b) {
    int blk = blockIdx.x;
    if (blk < 2016) {
        int i = blk * 256 + threadIdx.x;
        packw_body(Wi, tin, Wig_b, CC, i);
    } else if (blk < 2592) {
        int i = (blk - 2016) * 256 + threadIdx.x;
        packw_body(Wgt, tg, Wig_b + (size_t)DFF * 1536, CC, i);
    } else {
        int i = (blk - 2592) * 256 + threadIdx.x;
        convert_body(Wu, Wout_b, i);
    }
}

// ---------------- bf16 MFMA GEMM: C = epi(A @ B^T) ----------------
// A: M x K bf16 row-major; B: N x K bf16 row-major. BM=128, BK=32, BN in {128,64}.
// 256 threads = 4 waves in 2x2; wave tile (64)x(BN/2); 16x16x32 MFMA frags.
// SWAP: grid (x=M-tile, y=N-tile) for L2 weight reuse on tall-N GEMMs.
// mode 0: Cf=acc (ld N); 1: Cf=acc+res; 2: Cf=acc*mul+res; 3: split at NS:
//   col<NS: Cb[row*NS+col]=bf16(relu(acc)^2); col>=NS: Cf[row*(N-NS)+col-NS]=sigmoid(acc)
template<int BN, bool SWAP>
__global__ __launch_bounds__(256) void mfma_gemm_kernel(
        const unsigned short* __restrict__ A, const unsigned short* __restrict__ B,
        float* __restrict__ Cf, unsigned short* __restrict__ Cb,
        int M, int N, int K, int mode, int NS,
        const float* __restrict__ mul, const float* __restrict__ res) {
    constexpr int BM = 128, BK = 32;
    constexpr int FN = BN / 32;
    __shared__ __align__(16) unsigned short As[BM * BK];
    __shared__ __align__(16) unsigned short Bs[BN * BK];
    const int tid = threadIdx.x;
    const int lane = tid & 63;
    const int w = tid >> 6;
    const int wm = w >> 1, wn = w & 1;
    const int m0 = (SWAP ? blockIdx.x : blockIdx.y) * BM;
    const int n0 = (SWAP ? blockIdx.y : blockIdx.x) * BN;
    const int quad = lane >> 4;
    const int l16 = lane & 15;

    floatx4 acc[4][FN];
    #pragma unroll
    for (int i = 0; i < 4; i++)
        #pragma unroll
        for (int j = 0; j < FN; j++) acc[i][j] = (floatx4){0.f, 0.f, 0.f, 0.f};

    int a_off[4], b_off[FN];
    #pragma unroll
    for (int mi = 0; mi < 4; mi++)
        a_off[mi] = (wm * 64 + mi * 16 + l16) * BK + quad * 8;
    #pragma unroll
    for (int ni = 0; ni < FN; ni++)
        b_off[ni] = (wn * (BN / 2) + ni * 16 + l16) * BK + quad * 8;

    for (int k0 = 0; k0 < K; k0 += BK) {
        const unsigned short* Ag = A + (size_t)m0 * K + k0;
        const unsigned short* Bg = B + (size_t)n0 * K + k0;
        #pragma unroll
        for (int i = 0; i < BM / 64; i++) {
            int c = i * 256 + tid;
            async16(Ag + (size_t)(c >> 2) * K + (c & 3) * 8, As + (i * 256 + w * 64) * 8);
        }
        #pragma unroll
        for (int i = 0; i < BN / 64; i++) {
            int c = i * 256 + tid;
            async16(Bg + (size_t)(c >> 2) * K + (c & 3) * 8, Bs + (i * 256 + w * 64) * 8);
        }
        __syncthreads();
        short8 af[4], bfr[FN];
        #pragma unroll
        for (int mi = 0; mi < 4; mi++) af[mi] = *(const short8*)(As + a_off[mi]);
        #pragma unroll
        for (int ni = 0; ni < FN; ni++) bfr[ni] = *(const short8*)(Bs + b_off[ni]);
        #pragma unroll
        for (int mi = 0; mi < 4; mi++)
            #pragma unroll
            for (int ni = 0; ni < FN; ni++)
                acc[mi][ni] = __builtin_amdgcn_mfma_f32_16x16x32_bf16(af[mi], bfr[ni], acc[mi][ni], 0, 0, 0);
        __syncthreads();
    }

    #pragma unroll
    for (int mi = 0; mi < 4; mi++) {
        #pragma unroll
        for (int ni = 0; ni < FN; ni++) {
            int col = n0 + wn * (BN / 2) + ni * 16 + l16;
            int row0 = m0 + wm * 64 + mi * 16 + quad * 4;
            #pragma unroll
            for (int r = 0; r < 4; r++) {
                float vval = acc[mi][ni][r];
                int row = row0 + r;
                if (mode == 0) {
                    Cf[(size_t)row * N + col] = vval;
                } else if (mode == 1) {
                    size_t off = (size_t)row * N + col;
                    Cf[off] = vval + res[off];
                } else if (mode == 2) {
                    size_t off = (size_t)row * N + col;
                    Cf[off] = vval * mul[off] + res[off];
                } else {
                    if (col < NS) {
                        float tpos = vval > 0.f ? vval : 0.f;
                        Cb[(size_t)row * NS + col] = f2b(tpos * tpos);
                    } else {
                        float sg = 1.f / (1.f + __expf(-vval));
                        Cf[(size_t)row * (N - NS) + (col - NS)] = sg;
                    }
                }
            }
        }
    }
}

// ---------------- WKV v3: LDS-batched scan, 4 waves/block sharing r/k -------------
// Block = (bh, vg): 4 waves, wave w handles v-column vg*4+w. Lane owns ONE k (=lane).
// r/k/v staged into double-buffered LDS in 16-step batches (coalesced float4 loads),
// so global latency hides under ~16 steps of compute. Reduce over k = 6x shfl_xor.
#define WKV_NB 16
__global__ __launch_bounds__(256) void wkv_kernel(
        const float* __restrict__ rkvg, const float* __restrict__ bonus,
        const float* __restrict__ decay, float* __restrict__ out) {
    const int blk = blockIdx.x;
    const int vg = blk & 15;
    const int bh = blk >> 4;
    const int b = bh / HH, h = bh % HH;
    const int tid = threadIdx.x;
    const int w = tid >> 6;       // wave 0..3 -> v column
    const int lane = tid & 63;    // k index
    const int vcol = vg * 4 + w;

    float u = bonus[h * KV + lane];
    float wdec = expf(-expf(decay[h * KV + lane]));
    float kv = 0.f;

    __shared__ float sr[2][WKV_NB][64];
    __shared__ float sk[2][WKV_NB][64];
    __shared__ float sv[2][WKV_NB][4];

    const float* base = rkvg + (size_t)(b * TT) * 3072 + h * KV;
    const int s_step = tid >> 4, s_l16 = tid & 15;

    // stage batch starting at t0 into buffer buf
    auto stage = [&](int buf, int t0) {
        const float* rp = base + (size_t)(t0 + s_step) * 3072;
        *(float4*)&sr[buf][s_step][s_l16 * 4] = *(const float4*)(rp + s_l16 * 4);
        *(float4*)&sk[buf][s_step][s_l16 * 4] = *(const float4*)(rp + 768 + s_l16 * 4);
        if (tid < WKV_NB * 4) {
            int st = tid >> 2, vv = tid & 3;
            sv[buf][st][vv] = base[(size_t)(t0 + st) * 3072 + 1536 + vg * 4 + vv];
        }
    };

    stage(0, 0);
    __syncthreads();

    float* op = out + (size_t)(b * TT) * CC + h * KV + vcol;

    for (int t0 = 0; t0 < TT; t0 += WKV_NB) {
        int buf = (t0 / WKV_NB) & 1;
        if (t0 + WKV_NB < TT) stage(buf ^ 1, t0 + WKV_NB);
        #pragma unroll
        for (int s = 0; s < WKV_NB; s++) {
            float rl = sr[buf][s][lane];
            float kl = sk[buf][s][lane];
            float vv = sv[buf][s][w];
            float a = kl * vv;
            float p = rl * fmaf(u, a, kv);
            kv = fmaf(kv, wdec, a);
            p += __shfl_xor(p, 1);
            p += __shfl_xor(p, 2);
            p += __shfl_xor(p, 4);
            p += __shfl_xor(p, 8);
            p += __shfl_xor(p, 16);
            p += __shfl_xor(p, 32);
            if (lane == 0) op[(size_t)(t0 + s) * CC] = p;
        }
        __syncthreads();   // ensures next batch staged AND this buf free to overwrite
    }
}

// ---------------- GroupNorm(eps=0.00064) * silu(g) -> bf16 ----------------
__global__ __launch_bounds__(64) void gn_silu_kernel(
        const float* __restrict__ wkvo, const float* __restrict__ rkvg,
        const float* __restrict__ gs, const float* __restrict__ gb,
        unsigned short* __restrict__ outb) {
    int gi = blockIdx.x;           // row*HH + h
    int vi = threadIdx.x;          // 0..63
    int h = gi % HH;
    int row = gi / HH;
    float val = wkvo[(size_t)gi * 64 + vi];
    float s1 = val;
    #pragma unroll
    for (int off = 32; off >= 1; off >>= 1) s1 += __shfl_xor(s1, off);
    float m = s1 * (1.f / 64.f);
    float d = val - m;
    float s2 = d * d;
    #pragma unroll
    for (int off = 32; off >= 1; off >>= 1) s2 += __shfl_xor(s2, off);
    float inv = rsqrtf(s2 * (1.f / 64.f) + 0.00064f);
    int c = h * 64 + vi;
    float gg = rkvg[(size_t)row * 3072 + 2304 + c];
    float sig = 1.f / (1.f + __expf(-gg));
    outb[(size_t)row * CC + c] = f2b((d * inv * gs[c] + gb[c]) * (gg * sig));
}

// ---------------- host ----------------
extern "C" void kernel_launch(void* const* d_in, const int* in_sizes, int n_in,
                              void* d_out, int out_size, void* d_ws, size_t ws_size,
                              hipStream_t stream) {
    const int*   tokens    = (const int*)  d_in[0];
    const float* embed     = (const float*)d_in[1];
    const float* emb_ln_s  = (const float*)d_in[2];
    const float* emb_ln_b  = (const float*)d_in[3];
    const float* tm_ln_s   = (const float*)d_in[4];
    const float* tm_ln_b   = (const float*)d_in[5];
    const float* ts_r      = (const float*)d_in[6];
    const float* ts_k      = (const float*)d_in[7];
    const float* ts_v      = (const float*)d_in[8];
    const float* ts_g      = (const float*)d_in[9];
    const float* W_r       = (const float*)d_in[10];
    const float* W_k       = (const float*)d_in[11];
    const float* W_v       = (const float*)d_in[12];
    const float* W_g       = (const float*)d_in[13];
    const float* W_o       = (const float*)d_in[14];
    const float* bonus     = (const float*)d_in[15];
    const float* decay     = (const float*)d_in[16];
    const float* gn_s      = (const float*)d_in[17];
    const float* gn_b      = (const float*)d_in[18];
    const float* cm_ln_s   = (const float*)d_in[19];
    const float* cm_ln_b   = (const float*)d_in[20];
    const float* cm_ts_in  = (const float*)d_in[21];
    const float* cm_ts_g   = (const float*)d_in[22];
    const float* W_in      = (const float*)d_in[23];
    const float* W_out     = (const float*)d_in[24];
    const float* W_gate    = (const float*)d_in[25];
    const float* head_ln_s = (const float*)d_in[26];
    const float* head_ln_b = (const float*)d_in[27];
    const float* W_unembed = (const float*)d_in[28];

    char* wsb = (char*)d_ws;
    // fp32 buffers
    float* hbuf = (float*)wsb;                 wsb += (size_t)MM * CC * 4;
    float* lnb  = (float*)wsb;                 wsb += (size_t)MM * CC * 4;
    float* rkvg = (float*)wsb;                 wsb += (size_t)MM * 3072 * 4;
    float* wkvo = (float*)wsb;                 wsb += (size_t)MM * CC * 4;
    float* gate = (float*)wsb;                 wsb += (size_t)MM * CC * 4;
    // bf16 buffers
    unsigned short* abuf   = (unsigned short*)wsb; wsb += (size_t)MM * 1536 * 2;
    unsigned short* tmo_b  = (unsigned short*)wsb; wsb += (size_t)MM * CC * 2;
    unsigned short* hid_b  = (unsigned short*)wsb; wsb += (size_t)MM * DFF * 2;
    unsigned short* lnh_b  = (unsigned short*)wsb; wsb += (size_t)MM * CC * 2;
    unsigned short* Wrkvg_b= (unsigned short*)wsb; wsb += (size_t)3072 * 1536 * 2;
    unsigned short* Wig_b  = (unsigned short*)wsb; wsb += (size_t)3456 * 1536 * 2;
    unsigned short* Wo_b   = (unsigned short*)wsb; wsb += (size_t)CC * CC * 2;
    unsigned short* Wout_b = (unsigned short*)wsb; wsb += (size_t)CC * DFF * 2;
    unsigned short* Wu_b   = (unsigned short*)wsb; wsb += (size_t)VV * CC * 2;

    dim3 b256(256);
    const int n4_un = VV * CC / 4;        // 9658368

    // embedding + LN
    ln_kernel<<<dim3(MM), b256, 0, stream>>>(embed, tokens, emb_ln_s, emb_ln_b, hbuf, nullptr);

    for (int l = 0; l < LL; l++) {
        const float* Wr = W_r + (size_t)l * CC * CC;
        const float* Wk = W_k + (size_t)l * CC * CC;
        const float* Wv = W_v + (size_t)l * CC * CC;
        const float* Wg = W_g + (size_t)l * CC * CC;
        const float* Wo = W_o + (size_t)l * CC * CC;
        const float* Wi = W_in  + (size_t)l * DFF * CC;
        const float* Wu = W_out + (size_t)l * CC * DFF;
        const float* Wgt= W_gate+ (size_t)l * CC * CC;

        // ---- time mixer ----
        prep_tm_kernel<<<dim3(5 * 576), b256, 0, stream>>>(
            Wr, Wk, Wv, Wg, Wo, ts_r + l*CC, ts_k + l*CC, ts_v + l*CC, ts_g + l*CC,
            Wrkvg_b, Wo_b);
        ln_a_kernel<<<dim3(MM), b256, 0, stream>>>(hbuf, tm_ln_s + l*CC, tm_ln_b + l*CC, abuf);
        // rkvg = [x,xs] @ Wrkvg^T : M=1024, N=3072, K=1536
        mfma_gemm_kernel<128, false><<<dim3(3072/128, MM/128), b256, 0, stream>>>(
            abuf, Wrkvg_b, rkvg, nullptr, MM, 3072, 1536, 0, 0, nullptr, nullptr);
        wkv_kernel<<<dim3(BB*HH*16), b256, 0, stream>>>(rkvg, bonus + l*HH*KV, decay + l*HH*KV, wkvo);
        gn_silu_kernel<<<dim3(MM*HH), dim3(64), 0, stream>>>(wkvo, rkvg, gn_s + l*CC, gn_b + l*CC, tmo_b);
        // h += tmo @ Wo^T : N=768, K=768
        mfma_gemm_kernel<64, false><<<dim3(CC/64, MM/128), b256, 0, stream>>>(
            tmo_b, Wo_b, hbuf, nullptr, MM, CC, CC, 1, 0, nullptr, hbuf);

        // ---- channel mixer ----
        prep_cm_kernel<<<dim3(4608), b256, 0, stream>>>(
            Wi, Wgt, Wu, cm_ts_in + l*CC, cm_ts_g + l*CC, Wig_b, Wout_b);
        ln_a_kernel<<<dim3(MM), b256, 0, stream>>>(hbuf, cm_ln_s + l*CC, cm_ln_b + l*CC, abuf);
        // [hid | gate] = [x,xs] @ Wig^T : N=3456, K=1536, split epilogue at NS=2688
        mfma_gemm_kernel<128, false><<<dim3(3456/128, MM/128), b256, 0, stream>>>(
            abuf, Wig_b, gate, hid_b, MM, 3456, 1536, 3, DFF, nullptr, nullptr);
        // h += (hid @ Wout^T) * gate : N=768, K=2688
        mfma_gemm_kernel<64, false><<<dim3(CC/64, MM/128), b256, 0, stream>>>(
            hid_b, Wout_b, hbuf, nullptr, MM, CC, DFF, 2, 0, gate, hbuf);
    }

    // head LN + unembed (grid swapped: x=M so 8 M-blocks share each B-tile in L2)
    ln_kernel<<<dim3(MM), b256, 0, stream>>>(hbuf, nullptr, head_ln_s, head_ln_b, lnb, lnh_b);
    convertw_kernel<<<dim3((n4_un + 255) / 256), b256, 0, stream>>>(W_unembed, Wu_b, n4_un);
    mfma_gemm_kernel<128, true><<<dim3(MM/128, VV/128), b256, 0, stream>>>(
        lnh_b, Wu_b, (float*)d_out, nullptr, MM, VV, CC, 0, 0, nullptr, nullptr);
}